// Round 10
// baseline (209.385 us; speedup 1.0000x reference)
//
#include <hip/hip_runtime.h>

// SynthesisStage: modulated conv2d w/ adaptive kernel selection.
// B=8, Ci=Co=256, H=W=128, K=3, N=4.
// v10 = v7 pipeline, re-balanced waves: 64co x 64px per wave (acc 64),
// block = 128co x 128px, 2048 blocks (cot-paired per XCD). Full af+bf
// register double-buffering (WAR-free: tile t+1's loads issue during tile
// t's MFMA). 1 raw s_barrier per (dh,kb) group; explicit vmcnt ledger
// {V20,V20,V4}; __launch_bounds__(256,3) targets 3 blocks/CU.

typedef __attribute__((ext_vector_type(4))) float f32x4;
typedef __attribute__((ext_vector_type(8))) short s16x8;

#define NB   8
#define NCI  256
#define NCO  256
#define NHW  128
#define NKER 4

#define SB0 __builtin_amdgcn_sched_barrier(0)
#define BAR __builtin_amdgcn_s_barrier()
#define WAITV(N) asm volatile("s_waitcnt vmcnt(" #N ")" ::: "memory")
#define WAITL0   asm volatile("s_waitcnt lgkmcnt(0)" ::: "memory")

__device__ __forceinline__ unsigned short f2bf(float f) {
  unsigned int u = __builtin_bit_cast(unsigned int, f);
  u += 0x7FFFu + ((u >> 16) & 1u);          // round-to-nearest-even
  return (unsigned short)(u >> 16);
}

// ---------------------------------------------------------------------------
// Kernel 1: modulated+demodulated weights -> bf16 in FRAGMENT-DIRECT order
// (identical to v7). Tile T=(b*9+tap)*8+kb is 16KB; af fragment for a
// 16-co group is one coalesced dwordx4 at T*16384 + co16grp*1024 + lane*16.
// ---------------------------------------------------------------------------
__global__ __launch_bounds__(256) void prep_k(
    const float* __restrict__ weight,    // [N][Co][Ci][3][3]
    const float* __restrict__ styles,    // [B][Ci]
    const float* __restrict__ selector,  // [B][N]
    unsigned short* __restrict__ wmod)   // fragment-ordered, 9.44 MB
{
  int bid = blockIdx.x;
  int b = bid >> 8, co = bid & 255;
  int ci = threadIdx.x;

  float sel[NKER];
#pragma unroll
  for (int n = 0; n < NKER; ++n) sel[n] = selector[b * NKER + n];

  float a[9];
#pragma unroll
  for (int j = 0; j < 9; ++j) a[j] = 0.f;
#pragma unroll
  for (int n = 0; n < NKER; ++n) {
    const float* wp = weight + (size_t)((n * NCO + co) * NCI + ci) * 9;
    float s = sel[n];
#pragma unroll
    for (int j = 0; j < 9; ++j) a[j] += s * wp[j];
  }
  float st = styles[b * NCI + ci];
  float ss = 0.f;
#pragma unroll
  for (int j = 0; j < 9; ++j) { a[j] *= st; ss += a[j] * a[j]; }

  for (int off = 32; off; off >>= 1) ss += __shfl_down(ss, off, 64);
  __shared__ float red[4];
  int wid = threadIdx.x >> 6, lane = threadIdx.x & 63;
  if (lane == 0) red[wid] = ss;
  __syncthreads();
  float tot = red[0] + red[1] + red[2] + red[3];
  float d = rsqrtf(tot + 1e-8f);

  int kb = ci >> 5;
  size_t base = (size_t)(co >> 4) * 512 +
                (size_t)(((ci & 31) >> 3) * 128) + ((co & 15) * 8) + (ci & 7);
#pragma unroll
  for (int j = 0; j < 9; ++j) {
    size_t T = (size_t)((b * 9 + j) * 8 + kb);
    wmod[(T << 13) + base] = f2bf(a[j] * d);
  }
}

// ---------------------------------------------------------------------------
// Kernel 2: implicit-GEMM conv; A direct-from-global (dbuf), B via 16KB LDS
// dbuf (dbuf'd frags). block = (b, h, cot); 4 waves of 64co x 64px; 72 tiles.
// ---------------------------------------------------------------------------
__global__ __launch_bounds__(256, 3) void conv_k(
    const float* __restrict__ x,              // [B][Ci][H][W] f32
    const unsigned short* __restrict__ wg,    // fragment-ordered wmod
    const float* __restrict__ noise,          // [B][Co][H][W]
    float* __restrict__ out)                  // [B][Co][H][W]
{
  extern __shared__ __align__(16) char XRs[]; // 2 x 8KB XR dbuf

  int orig = blockIdx.x;             // 2048 blocks
  int b = orig & 7;                  // XCD-resident sample
  int rem = orig >> 3;               // (h, cot) adjacent -> x L2/L1 shared
  int h = rem >> 1;
  int cot = rem & 1;

  int t = threadIdx.x;
  int lane = t & 63;
  int wid = t >> 6;
  int wr = wid >> 1, wc = wid & 1;   // co half / px half
  int ll = lane & 15;
  int ks = lane >> 4;                // k-slice 0..3

  f32x4 acc[4][4];
#pragma unroll
  for (int m = 0; m < 4; ++m)
#pragma unroll
    for (int n = 0; n < 4; ++n) acc[m][n] = (f32x4){0.f, 0.f, 0.f, 0.f};

  // x staging: thread owns ci-pair (c,c+1) x 8 w's (w = wi + 16*j2)
  int c = ((t >> 4) & 15) * 2;
  int wi = t & 15;
  float xlo[8], xhi[8];
  unsigned xmask = 0xFFFFFFFFu;

  auto issueX = [&](int g) {
    int gc = g < 24 ? g : 23;
    int dh = gc >> 3, kb = gc & 7;
    int hy = h + dh - 1;
    xmask = ((unsigned)hy < 128u) ? 0xFFFFFFFFu : 0u;
    int hyc = hy < 0 ? 0 : (hy > 127 ? 127 : hy);
    const float* base = x + ((size_t)(b * NCI + kb * 32 + c) * NHW + hyc) * NHW + wi;
#pragma unroll
    for (int j2 = 0; j2 < 8; ++j2) {
      xlo[j2] = base[j2 * 16];
      xhi[j2] = base[NHW * NHW + j2 * 16];
    }
  };

  // A-fragments straight from global (fragment-ordered tile, coalesced)
  auto issueAF = [&](int tc, s16x8* af) {
    if (tc > 71) tc = 71;
    int g = tc / 3, tap = tc - g * 3;
    int dh = g >> 3, kb = g & 7;
    const char* src = (const char*)wg +
        ((size_t)((b * 9 + dh * 3 + tap) * 8 + kb) << 14) +
        cot * 8192 + wr * 4096 + lane * 16;
#pragma unroll
    for (int m = 0; m < 4; ++m)
      af[m] = *(const s16x8*)(src + m * 1024);
  };

  auto packXR = [&](int g) {
    char* dstb = XRs + (g & 1) * 8192;
    int slot = (((wi & 1) << 2) + (c >> 3)) ^ ((wi >> 1) & 7);
    char* p0 = dstb + (wi >> 1) * 128 + (slot << 4) + ((c & 7) << 1);
#pragma unroll
    for (int j2 = 0; j2 < 8; ++j2) {
      unsigned pk = ((unsigned)f2bf(xhi[j2]) << 16) | f2bf(xlo[j2]);
      *(unsigned*)(p0 + j2 * 1024) = pk & xmask;  // zero-fill border rows
    }
  };

// B-fragments: wave px window = wc*64 + [0,64); edge clamp+select only at
// (DW0,n0) [underflow when wc==0] and (DW2,n3) [overflow when wc==1].
#define PFB(XRBASE, DW, bf)                                              \
  {                                                                      \
    const char* Xb = (XRBASE);                                           \
    _Pragma("unroll")                                                    \
    for (int n = 0; n < 4; ++n) {                                        \
      int wn = wc * 64 + n * 16 + ll + (DW) - 1;                         \
      if (((DW) == 0 && n == 0) || ((DW) == 2 && n == 3)) {              \
        int wx = wn < 0 ? 0 : (wn > 127 ? 127 : wn);                     \
        int row = wx >> 1;                                               \
        int slot = (((wx & 1) << 2) + ks) ^ (row & 7);                   \
        s16x8 bv = *(const s16x8*)(Xb + row * 128 + (slot << 4));        \
        if (wn != wx) { s16x8 z = {0, 0, 0, 0, 0, 0, 0, 0}; bv = z; }    \
        bf[n] = bv;                                                      \
      } else {                                                           \
        int row = wn >> 1;                                               \
        int slot = (((wn & 1) << 2) + ks) ^ (row & 7);                   \
        bf[n] = *(const s16x8*)(Xb + row * 128 + (slot << 4));           \
      }                                                                  \
    }                                                                    \
  }

#define MFMA16(af, bf)                                                   \
  __builtin_amdgcn_s_setprio(1);                                         \
  _Pragma("unroll")                                                      \
  for (int m = 0; m < 4; ++m)                                            \
    _Pragma("unroll")                                                    \
    for (int n = 0; n < 4; ++n)                                          \
      acc[m][n] = __builtin_amdgcn_mfma_f32_16x16x32_bf16(               \
          af[m], bf[n], acc[m][n], 0, 0, 0);                             \
  __builtin_amdgcn_s_setprio(0);

  s16x8 afA[4], afB[4], bf0[4], bf1[4];

  // ---- prologue: x(0) [16], af(0)->afB [4]; pack XR(0) ----
  issueX(0); SB0;
  issueAF(0, afB); SB0;
  WAITV(4); SB0;                     // drain x(0); keep af(0)
  packXR(0);

  // ---- main loop: 12 x 6 tiles (2 groups); 1 barrier per group ----
  // ledger (outstanding after wait): t0 V(20)=af(t+1)4+x16, t1 V(20),
  // t2 V(4)=af(next t0) only (x drained for pack).
#pragma unroll 1
  for (int gg = 0; gg < 12; ++gg) {
    int g0 = gg * 2, t0 = gg * 6;
    // ---- group g0 (xr buf0) ----
    WAITL0; SB0; BAR; SB0;
    PFB(XRs, 0, bf0);
    PFB(XRs, 1, bf1);
    issueAF(t0 + 1, afA); SB0;
    issueX(g0 + 1); SB0;
    WAITV(20); SB0;
    MFMA16(afB, bf0);                // tau0
    issueAF(t0 + 2, afB); SB0;
    PFB(XRs, 2, bf0);
    WAITV(20); SB0;
    MFMA16(afA, bf1);                // tau1
    issueAF(t0 + 3, afA); SB0;
    WAITV(4); SB0;
    packXR(g0 + 1);
    MFMA16(afB, bf0);                // tau2 (lgkm: frag reads before pack wr)
    // ---- group g0+1 (xr buf1) ----
    WAITL0; SB0; BAR; SB0;
    PFB(XRs + 8192, 0, bf0);
    PFB(XRs + 8192, 1, bf1);
    issueAF(t0 + 4, afB); SB0;
    issueX(g0 + 2); SB0;
    WAITV(20); SB0;
    MFMA16(afA, bf0);                // tau3
    issueAF(t0 + 5, afA); SB0;
    PFB(XRs + 8192, 2, bf0);
    WAITV(20); SB0;
    MFMA16(afB, bf1);                // tau4
    issueAF(t0 + 6, afB); SB0;
    WAITV(4); SB0;
    packXR(g0 + 2);
    MFMA16(afA, bf0);                // tau5
  }

  // epilogue: D[row=ks*4+j][col=ll], fused noise add
  int pr4 = ks * 4;
#pragma unroll
  for (int m = 0; m < 4; ++m) {
#pragma unroll
    for (int n = 0; n < 4; ++n) {
      int px = wc * 64 + n * 16 + ll;
#pragma unroll
      for (int j = 0; j < 4; ++j) {
        int co = cot * 128 + wr * 64 + m * 16 + pr4 + j;
        size_t idx = ((size_t)(b * NCO + co) * NHW + h) * NHW + px;
        out[idx] = acc[m][n][j] + noise[idx];
      }
    }
  }
}

// ---------------------------------------------------------------------------
extern "C" void kernel_launch(void* const* d_in, const int* in_sizes, int n_in,
                              void* d_out, int out_size, void* d_ws, size_t ws_size,
                              hipStream_t stream) {
  const float* x        = (const float*)d_in[0];
  const float* weight   = (const float*)d_in[1];
  const float* styles   = (const float*)d_in[2];
  const float* selector = (const float*)d_in[3];
  const float* noise    = (const float*)d_in[4];
  float* out = (float*)d_out;

  // workspace: ONLY wmod (fragment-ordered) = 9,437,184 bytes
  unsigned short* wmod = (unsigned short*)d_ws;

  hipLaunchKernelGGL(prep_k, dim3(NB * NCO), dim3(256), 0, stream,
                     weight, styles, selector, wmod);
  hipLaunchKernelGGL(conv_k, dim3(NB * 2 * NHW), dim3(256), 16 * 1024, stream,
                     x, wmod, noise, out);
}

// Round 11
// 201.823 us; speedup vs baseline: 1.0375x; 1.0375x over previous
//
#include <hip/hip_runtime.h>

// SynthesisStage: modulated conv2d w/ adaptive kernel selection.
// B=8, Ci=Co=256, H=W=128, K=3, N=4.
// v11 = v7 with the wave grid re-shaped 4x1 -> 2x2 (wave = 128co x 64px):
// halves per-block LDS B-fragment reads (the binding resource in v7's
// accounting); af comes from L2/L1 (fragment-ordered wmod). Everything
// else identical to v7: 1 raw s_barrier per (dh,kb) group, compiler-
// counted vmcnt, reg-staged x -> packed XR dbuf, setprio around MFMA.

typedef __attribute__((ext_vector_type(4))) float f32x4;
typedef __attribute__((ext_vector_type(8))) short s16x8;

#define NB   8
#define NCI  256
#define NCO  256
#define NHW  128
#define NKER 4

#define SB0 __builtin_amdgcn_sched_barrier(0)
#define BAR __builtin_amdgcn_s_barrier()
#define WAITL0 asm volatile("s_waitcnt lgkmcnt(0)" ::: "memory")

__device__ __forceinline__ unsigned short f2bf(float f) {
  unsigned int u = __builtin_bit_cast(unsigned int, f);
  u += 0x7FFFu + ((u >> 16) & 1u);          // round-to-nearest-even
  return (unsigned short)(u >> 16);
}

// ---------------------------------------------------------------------------
// Kernel 1: modulated+demodulated weights -> bf16 in FRAGMENT-DIRECT order
// (identical to v7). Tile T=(b*9+tap)*8+kb is 16KB; the af fragment for
// 16-co group g16 is one coalesced dwordx4 at T*16384 + g16*1024 + lane*16.
// ---------------------------------------------------------------------------
__global__ __launch_bounds__(256) void prep_k(
    const float* __restrict__ weight,    // [N][Co][Ci][3][3]
    const float* __restrict__ styles,    // [B][Ci]
    const float* __restrict__ selector,  // [B][N]
    unsigned short* __restrict__ wmod)   // fragment-ordered, 9.44 MB
{
  int bid = blockIdx.x;
  int b = bid >> 8, co = bid & 255;
  int ci = threadIdx.x;

  float sel[NKER];
#pragma unroll
  for (int n = 0; n < NKER; ++n) sel[n] = selector[b * NKER + n];

  float a[9];
#pragma unroll
  for (int j = 0; j < 9; ++j) a[j] = 0.f;
#pragma unroll
  for (int n = 0; n < NKER; ++n) {
    const float* wp = weight + (size_t)((n * NCO + co) * NCI + ci) * 9;
    float s = sel[n];
#pragma unroll
    for (int j = 0; j < 9; ++j) a[j] += s * wp[j];
  }
  float st = styles[b * NCI + ci];
  float ss = 0.f;
#pragma unroll
  for (int j = 0; j < 9; ++j) { a[j] *= st; ss += a[j] * a[j]; }

  for (int off = 32; off; off >>= 1) ss += __shfl_down(ss, off, 64);
  __shared__ float red[4];
  int wid = threadIdx.x >> 6, lane = threadIdx.x & 63;
  if (lane == 0) red[wid] = ss;
  __syncthreads();
  float tot = red[0] + red[1] + red[2] + red[3];
  float d = rsqrtf(tot + 1e-8f);

  int kb = ci >> 5;
  size_t base = (size_t)(co >> 4) * 512 +
                (size_t)(((ci & 31) >> 3) * 128) + ((co & 15) * 8) + (ci & 7);
#pragma unroll
  for (int j = 0; j < 9; ++j) {
    size_t T = (size_t)((b * 9 + j) * 8 + kb);
    wmod[(T << 13) + base] = f2bf(a[j] * d);
  }
}

// ---------------------------------------------------------------------------
// Kernel 2: implicit-GEMM conv; A direct-from-global, B via 16KB LDS dbuf.
// block = (b, h); 4 waves in a 2x2 grid, wave tile 128co x 64px; 72 K-tiles.
// ---------------------------------------------------------------------------
__global__ __launch_bounds__(256, 2) void conv_k(
    const float* __restrict__ x,              // [B][Ci][H][W] f32
    const unsigned short* __restrict__ wg,    // fragment-ordered wmod
    const float* __restrict__ noise,          // [B][Co][H][W]
    float* __restrict__ out)                  // [B][Co][H][W]
{
  extern __shared__ __align__(16) char XRs[]; // 2 x 8KB XR dbuf

  int orig = blockIdx.x;             // 1024 blocks
  int b = orig & 7;                  // XCD-resident sample
  int h = orig >> 3;

  int t = threadIdx.x;
  int lane = t & 63;
  int wid = t >> 6;
  int wr = wid >> 1, wc = wid & 1;   // 2x2 wave grid: co half / px half
  int ll = lane & 15;
  int ks = lane >> 4;                // k-slice 0..3

  f32x4 acc[8][4];
#pragma unroll
  for (int m = 0; m < 8; ++m)
#pragma unroll
    for (int n = 0; n < 4; ++n) acc[m][n] = (f32x4){0.f, 0.f, 0.f, 0.f};

  // x staging: thread owns ci-pair (c,c+1) x 8 w's (w = wi + 16*j2)
  int c = ((t >> 4) & 15) * 2;
  int wi = t & 15;
  float xlo[8], xhi[8];
  unsigned xmask = 0xFFFFFFFFu;

  auto issueX = [&](int g) {
    int gc = g < 24 ? g : 23;
    int dh = gc >> 3, kb = gc & 7;
    int hy = h + dh - 1;
    xmask = ((unsigned)hy < 128u) ? 0xFFFFFFFFu : 0u;
    int hyc = hy < 0 ? 0 : (hy > 127 ? 127 : hy);
    const float* base = x + ((size_t)(b * NCI + kb * 32 + c) * NHW + hyc) * NHW + wi;
#pragma unroll
    for (int j2 = 0; j2 < 8; ++j2) {
      xlo[j2] = base[j2 * 16];
      xhi[j2] = base[NHW * NHW + j2 * 16];
    }
  };

  // A-fragments straight from global (fragment-ordered tile, coalesced);
  // wave covers co = wr*128 + m*16 + [0,16), m = 0..7.
  auto issueAF = [&](int tc, s16x8* af) {
    if (tc > 71) tc = 71;
    int g = tc / 3, tap = tc - g * 3;
    int dh = g >> 3, kb = g & 7;
    const char* src = (const char*)wg +
        ((size_t)((b * 9 + dh * 3 + tap) * 8 + kb) << 14) +
        wr * 8192 + lane * 16;
#pragma unroll
    for (int m = 0; m < 8; ++m)
      af[m] = *(const s16x8*)(src + m * 1024);
  };

  auto packXR = [&](int g) {
    char* dstb = XRs + (g & 1) * 8192;
    int slot = (((wi & 1) << 2) + (c >> 3)) ^ ((wi >> 1) & 7);
    char* p0 = dstb + (wi >> 1) * 128 + (slot << 4) + ((c & 7) << 1);
#pragma unroll
    for (int j2 = 0; j2 < 8; ++j2) {
      unsigned pk = ((unsigned)f2bf(xhi[j2]) << 16) | f2bf(xlo[j2]);
      *(unsigned*)(p0 + j2 * 1024) = pk & xmask;  // zero-fill border rows
    }
  };

// B-fragments: wave px window = wc*64 + [0,64); edge clamp+select only at
// (DW0,n0) [underflow, wc==0] and (DW2,n3) [overflow, wc==1].
#define PFB(XRBASE, DW, bf)                                              \
  {                                                                      \
    const char* Xb = (XRBASE);                                           \
    _Pragma("unroll")                                                    \
    for (int n = 0; n < 4; ++n) {                                        \
      int wn = wc * 64 + n * 16 + ll + (DW) - 1;                         \
      if (((DW) == 0 && n == 0) || ((DW) == 2 && n == 3)) {              \
        int wx = wn < 0 ? 0 : (wn > 127 ? 127 : wn);                     \
        int row = wx >> 1;                                               \
        int slot = (((wx & 1) << 2) + ks) ^ (row & 7);                   \
        s16x8 bv = *(const s16x8*)(Xb + row * 128 + (slot << 4));        \
        if (wn != wx) { s16x8 z = {0, 0, 0, 0, 0, 0, 0, 0}; bv = z; }    \
        bf[n] = bv;                                                      \
      } else {                                                           \
        int row = wn >> 1;                                               \
        int slot = (((wn & 1) << 2) + ks) ^ (row & 7);                   \
        bf[n] = *(const s16x8*)(Xb + row * 128 + (slot << 4));           \
      }                                                                  \
    }                                                                    \
  }

#define MFMA32(af, bf)                                                   \
  __builtin_amdgcn_s_setprio(1);                                         \
  _Pragma("unroll")                                                      \
  for (int m = 0; m < 8; ++m)                                            \
    _Pragma("unroll")                                                    \
    for (int n = 0; n < 4; ++n)                                          \
      acc[m][n] = __builtin_amdgcn_mfma_f32_16x16x32_bf16(               \
          af[m], bf[n], acc[m][n], 0, 0, 0);                             \
  __builtin_amdgcn_s_setprio(0);

  s16x8 afA[8], afB[8], bf[4];

  // ---- prologue: x(0), af(0)->A; pack XR(0) ----
  issueX(0); SB0;
  issueAF(0, afA); SB0;
  packXR(0);                          // compiler waits x via counted vmcnt

  // ---- main loop: 12 x 6 tiles (2 groups); 1 barrier per group ----
#pragma unroll 1
  for (int gg = 0; gg < 12; ++gg) {
    int g0 = gg * 2, t0 = gg * 6;
    // T0: group g0 (xr buf0), tap0, af=afA
    WAITL0; SB0; BAR; SB0;
    PFB(XRs, 0, bf);
    issueAF(t0 + 1, afB); SB0;
    issueX(g0 + 1); SB0;
    MFMA32(afA, bf);
    // T1: tap1, af=afB
    PFB(XRs, 1, bf);
    issueAF(t0 + 2, afA); SB0;
    MFMA32(afB, bf);
    // T2: tap2, af=afA
    PFB(XRs, 2, bf);
    issueAF(t0 + 3, afB); SB0;
    packXR(g0 + 1);
    MFMA32(afA, bf);
    // T3: group g0+1 (xr buf1), tap0, af=afB
    WAITL0; SB0; BAR; SB0;
    PFB(XRs + 8192, 0, bf);
    issueAF(t0 + 4, afA); SB0;
    issueX(g0 + 2); SB0;
    MFMA32(afB, bf);
    // T4: tap1, af=afA
    PFB(XRs + 8192, 1, bf);
    issueAF(t0 + 5, afB); SB0;
    MFMA32(afA, bf);
    // T5: tap2, af=afB
    PFB(XRs + 8192, 2, bf);
    issueAF(t0 + 6, afA); SB0;
    packXR(g0 + 2);
    MFMA32(afB, bf);
  }

  // epilogue: D[row=ks*4+j][col=ll], fused noise add
  int pr4 = ks * 4;
#pragma unroll
  for (int m = 0; m < 8; ++m) {
#pragma unroll
    for (int n = 0; n < 4; ++n) {
      int px = wc * 64 + n * 16 + ll;
#pragma unroll
      for (int j = 0; j < 4; ++j) {
        int co = wr * 128 + m * 16 + pr4 + j;
        size_t idx = ((size_t)(b * NCO + co) * NHW + h) * NHW + px;
        out[idx] = acc[m][n][j] + noise[idx];
      }
    }
  }
}

// ---------------------------------------------------------------------------
extern "C" void kernel_launch(void* const* d_in, const int* in_sizes, int n_in,
                              void* d_out, int out_size, void* d_ws, size_t ws_size,
                              hipStream_t stream) {
  const float* x        = (const float*)d_in[0];
  const float* weight   = (const float*)d_in[1];
  const float* styles   = (const float*)d_in[2];
  const float* selector = (const float*)d_in[3];
  const float* noise    = (const float*)d_in[4];
  float* out = (float*)d_out;

  // workspace: ONLY wmod (fragment-ordered) = 9,437,184 bytes
  unsigned short* wmod = (unsigned short*)d_ws;

  hipLaunchKernelGGL(prep_k, dim3(NB * NCO), dim3(256), 0, stream,
                     weight, styles, selector, wmod);
  hipLaunchKernelGGL(conv_k, dim3(NB * NHW), dim3(256), 16 * 1024, stream,
                     x, wmod, noise, out);
}

// Round 12
// 174.415 us; speedup vs baseline: 1.2005x; 1.1571x over previous
//
#include <hip/hip_runtime.h>

// SynthesisStage: modulated conv2d w/ adaptive kernel selection.
// B=8, Ci=Co=256, H=W=128, K=3, N=4.
// v12 = v7 with the per-tile LDS read burst software-pipelined INTO the
// previous tap's MFMA burst: per n, {ds_read bf(tap+1)[n]; 4x MFMA(tap)}
// pinned by sched_group_barrier. bf registers rotate in place (tmp->bfc[n]).
// Edge px handled by address-redirect to a zero slot (no post-load select).
// Everything else identical to v7: af direct global->VGPR dbuf, XR dbuf,
// 1 raw s_barrier per (dh,kb) group, compiler-counted vmcnt, setprio.

typedef __attribute__((ext_vector_type(4))) float f32x4;
typedef __attribute__((ext_vector_type(8))) short s16x8;

#define NB   8
#define NCI  256
#define NCO  256
#define NHW  128
#define NKER 4

#define SB0 __builtin_amdgcn_sched_barrier(0)
#define BAR __builtin_amdgcn_s_barrier()
#define WAITL0 asm volatile("s_waitcnt lgkmcnt(0)" ::: "memory")
#define ZOFF 16384   // 256B zero slot after the two 8KB XR buffers

__device__ __forceinline__ unsigned short f2bf(float f) {
  unsigned int u = __builtin_bit_cast(unsigned int, f);
  u += 0x7FFFu + ((u >> 16) & 1u);          // round-to-nearest-even
  return (unsigned short)(u >> 16);
}

// ---------------------------------------------------------------------------
// Kernel 1: modulated+demodulated weights -> bf16 in FRAGMENT-DIRECT order
// (identical to v7). Tile T=(b*9+tap)*8+kb is 16KB; conv_k wave wid reads
// af[m] as one coalesced dwordx4 at T*16384 + wid*4096 + m*1024 + lane*16.
// ---------------------------------------------------------------------------
__global__ __launch_bounds__(256) void prep_k(
    const float* __restrict__ weight,    // [N][Co][Ci][3][3]
    const float* __restrict__ styles,    // [B][Ci]
    const float* __restrict__ selector,  // [B][N]
    unsigned short* __restrict__ wmod)   // fragment-ordered, 9.44 MB
{
  int bid = blockIdx.x;
  int b = bid >> 8, co = bid & 255;
  int ci = threadIdx.x;

  float sel[NKER];
#pragma unroll
  for (int n = 0; n < NKER; ++n) sel[n] = selector[b * NKER + n];

  float a[9];
#pragma unroll
  for (int j = 0; j < 9; ++j) a[j] = 0.f;
#pragma unroll
  for (int n = 0; n < NKER; ++n) {
    const float* wp = weight + (size_t)((n * NCO + co) * NCI + ci) * 9;
    float s = sel[n];
#pragma unroll
    for (int j = 0; j < 9; ++j) a[j] += s * wp[j];
  }
  float st = styles[b * NCI + ci];
  float ss = 0.f;
#pragma unroll
  for (int j = 0; j < 9; ++j) { a[j] *= st; ss += a[j] * a[j]; }

  for (int off = 32; off; off >>= 1) ss += __shfl_down(ss, off, 64);
  __shared__ float red[4];
  int wid = threadIdx.x >> 6, lane = threadIdx.x & 63;
  if (lane == 0) red[wid] = ss;
  __syncthreads();
  float tot = red[0] + red[1] + red[2] + red[3];
  float d = rsqrtf(tot + 1e-8f);

  int kb = ci >> 5;
  size_t base = (size_t)(co >> 4) * 512 +
                (size_t)(((ci & 31) >> 3) * 128) + ((co & 15) * 8) + (ci & 7);
#pragma unroll
  for (int j = 0; j < 9; ++j) {
    size_t T = (size_t)((b * 9 + j) * 8 + kb);
    wmod[(T << 13) + base] = f2bf(a[j] * d);
  }
}

// ---------------------------------------------------------------------------
// Kernel 2: implicit-GEMM conv; A direct-from-global, B via 16KB LDS dbuf.
// block = (b, h); 256 thr = 4 waves, wave tile 64co x 128px; 72 K-tiles.
// ---------------------------------------------------------------------------
__global__ __launch_bounds__(256, 2) void conv_k(
    const float* __restrict__ x,              // [B][Ci][H][W] f32
    const unsigned short* __restrict__ wg,    // fragment-ordered wmod
    const float* __restrict__ noise,          // [B][Co][H][W]
    float* __restrict__ out)                  // [B][Co][H][W]
{
  extern __shared__ __align__(16) char XRs[]; // 2x8KB XR dbuf + 256B zeros

  int orig = blockIdx.x;             // 1024 blocks
  int b = orig & 7;                  // XCD-resident sample
  int h = orig >> 3;

  int t = threadIdx.x;
  int lane = t & 63;
  int wid = t >> 6;
  int cow = wid << 6;
  int ll = lane & 15;
  int ks = lane >> 4;                // k-slice 0..3

  f32x4 acc[4][8];
#pragma unroll
  for (int m = 0; m < 4; ++m)
#pragma unroll
    for (int n = 0; n < 8; ++n) acc[m][n] = (f32x4){0.f, 0.f, 0.f, 0.f};

  // x staging: thread owns ci-pair (c,c+1) x 8 w's (w = wi + 16*j2)
  int c = ((t >> 4) & 15) * 2;
  int wi = t & 15;
  float xlo[8], xhi[8];
  unsigned xmask = 0xFFFFFFFFu;

  auto issueX = [&](int g) {
    int gc = g < 24 ? g : 23;
    int dh = gc >> 3, kb = gc & 7;
    int hy = h + dh - 1;
    xmask = ((unsigned)hy < 128u) ? 0xFFFFFFFFu : 0u;
    int hyc = hy < 0 ? 0 : (hy > 127 ? 127 : hy);
    const float* base = x + ((size_t)(b * NCI + kb * 32 + c) * NHW + hyc) * NHW + wi;
#pragma unroll
    for (int j2 = 0; j2 < 8; ++j2) {
      xlo[j2] = base[j2 * 16];
      xhi[j2] = base[NHW * NHW + j2 * 16];
    }
  };

  // A-fragments straight from global (fragment-ordered tile, coalesced)
  auto issueAF = [&](int tc, s16x8* af) {
    if (tc > 71) tc = 71;
    int g = tc / 3, tap = tc - g * 3;
    int dh = g >> 3, kb = g & 7;
    const char* src = (const char*)wg +
        ((size_t)((b * 9 + dh * 3 + tap) * 8 + kb) << 14) + wid * 4096 + lane * 16;
#pragma unroll
    for (int m = 0; m < 4; ++m)
      af[m] = *(const s16x8*)(src + m * 1024);
  };

  auto packXR = [&](int g) {
    char* dstb = XRs + (g & 1) * 8192;
    int slot = (((wi & 1) << 2) + (c >> 3)) ^ ((wi >> 1) & 7);
    char* p0 = dstb + (wi >> 1) * 128 + (slot << 4) + ((c & 7) << 1);
#pragma unroll
    for (int j2 = 0; j2 < 8; ++j2) {
      unsigned pk = ((unsigned)f2bf(xhi[j2]) << 16) | f2bf(xlo[j2]);
      *(unsigned*)(p0 + j2 * 1024) = pk & xmask;  // zero-fill border rows
    }
  };

// single B-fragment read; OOB px (only DW0/n0 underflow, DW2/n7 overflow)
// redirects the ADDRESS to the zero slot (no post-load select).
#define RDB(BUFOFF, DW, n, dst)                                          \
  {                                                                      \
    int wn = (n) * 16 + ll + (DW) - 1;                                   \
    int row = wn >> 1;                                                   \
    int slot = (((wn & 1) << 2) + ks) ^ (row & 7);                       \
    int a = (BUFOFF) + row * 128 + (slot << 4);                          \
    if (((DW) == 0 && (n) == 0) || ((DW) == 2 && (n) == 7)) {            \
      if ((unsigned)wn > 127u) a = ZOFF + (ks << 4);                     \
    }                                                                    \
    dst = *(const s16x8*)(XRs + a);                                      \
  }

// plain 8-read burst (group-start, tap0)
#define PFB0(BUFOFF, DW, bf)                                             \
  {                                                                      \
    _Pragma("unroll")                                                    \
    for (int n = 0; n < 8; ++n) RDB(BUFOFF, DW, n, bf[n]);               \
  }

// MFMA burst for current tap interleaved with reads of tap DWN (same group):
// per n: {1 ds_read ; 4 MFMA} pinned by sched_group_barrier.
#define TILE_ILV(AF, DWN, BUFOFF)                                        \
  __builtin_amdgcn_s_setprio(1);                                         \
  _Pragma("unroll")                                                      \
  for (int n = 0; n < 8; ++n) {                                          \
    s16x8 tnew;                                                          \
    RDB(BUFOFF, DWN, n, tnew);                                           \
    __builtin_amdgcn_sched_group_barrier(0x100, 1, 0);                   \
    _Pragma("unroll")                                                    \
    for (int m = 0; m < 4; ++m)                                          \
      acc[m][n] = __builtin_amdgcn_mfma_f32_16x16x32_bf16(               \
          AF[m], bfc[n], acc[m][n], 0, 0, 0);                            \
    __builtin_amdgcn_sched_group_barrier(0x008, 4, 0);                   \
    bfc[n] = tnew;                                                       \
  }                                                                      \
  __builtin_amdgcn_s_setprio(0);

// last tap of the group: MFMA only
#define TILE_LAST(AF)                                                    \
  __builtin_amdgcn_s_setprio(1);                                         \
  _Pragma("unroll")                                                      \
  for (int n = 0; n < 8; ++n)                                            \
    _Pragma("unroll")                                                    \
    for (int m = 0; m < 4; ++m)                                          \
      acc[m][n] = __builtin_amdgcn_mfma_f32_16x16x32_bf16(               \
          AF[m], bfc[n], acc[m][n], 0, 0, 0);                            \
  __builtin_amdgcn_s_setprio(0);

  s16x8 afA[4], afB[4], bfc[8];

  // ---- prologue: zero slot; x(0); af(0)->afA; pack XR(0) ----
  if (t < 16)
    *(f32x4*)(XRs + ZOFF + t * 16) = (f32x4){0.f, 0.f, 0.f, 0.f};
  issueX(0); SB0;
  issueAF(0, afA); SB0;
  packXR(0);                          // compiler waits x via counted vmcnt

  // ---- main loop: 12 x 2 groups x 3 taps; 1 barrier per group ----
#pragma unroll 1
  for (int gg = 0; gg < 12; ++gg) {
    int g0 = gg * 2, t0 = gg * 6;
    // ---- group g0 (xr buf0) ----
    WAITL0; SB0; BAR; SB0;
    PFB0(0, 0, bfc);                  // tap0 reads (exposed)
    issueAF(t0 + 1, afB); SB0;
    issueX(g0 + 1); SB0;
    TILE_ILV(afA, 1, 0);              // MFMA tap0 + read tap1
    issueAF(t0 + 2, afA); SB0;
    TILE_ILV(afB, 2, 0);              // MFMA tap1 + read tap2
    issueAF(t0 + 3, afB); SB0;
    packXR(g0 + 1);
    TILE_LAST(afA);                   // MFMA tap2
    // ---- group g0+1 (xr buf1) ----
    WAITL0; SB0; BAR; SB0;
    PFB0(8192, 0, bfc);
    issueAF(t0 + 4, afA); SB0;
    issueX(g0 + 2); SB0;
    TILE_ILV(afB, 1, 8192);
    issueAF(t0 + 5, afB); SB0;
    TILE_ILV(afA, 2, 8192);
    issueAF(t0 + 6, afA); SB0;
    packXR(g0 + 2);
    TILE_LAST(afB);
  }

  // epilogue: D[row=ks*4+j][col=ll], fused noise add
  int pr4 = ks * 4;
#pragma unroll
  for (int m = 0; m < 4; ++m) {
#pragma unroll
    for (int n = 0; n < 8; ++n) {
      int px = n * 16 + ll;
#pragma unroll
      for (int j = 0; j < 4; ++j) {
        int co = cow + m * 16 + pr4 + j;
        size_t idx = ((size_t)(b * NCO + co) * NHW + h) * NHW + px;
        out[idx] = acc[m][n][j] + noise[idx];
      }
    }
  }
}

// ---------------------------------------------------------------------------
extern "C" void kernel_launch(void* const* d_in, const int* in_sizes, int n_in,
                              void* d_out, int out_size, void* d_ws, size_t ws_size,
                              hipStream_t stream) {
  const float* x        = (const float*)d_in[0];
  const float* weight   = (const float*)d_in[1];
  const float* styles   = (const float*)d_in[2];
  const float* selector = (const float*)d_in[3];
  const float* noise    = (const float*)d_in[4];
  float* out = (float*)d_out;

  // workspace: ONLY wmod (fragment-ordered) = 9,437,184 bytes
  unsigned short* wmod = (unsigned short*)d_ws;

  hipLaunchKernelGGL(prep_k, dim3(NB * NCO), dim3(256), 0, stream,
                     weight, styles, selector, wmod);
  hipLaunchKernelGGL(conv_k, dim3(NB * NHW), dim3(256), 16640, stream,
                     x, wmod, noise, out);
}